// Round 1
// baseline (1110.756 us; speedup 1.0000x reference)
//
#include <hip/hip_runtime.h>
#include <math.h>

// Problem constants (match reference)
constexpr int N   = 16384;
constexpr int E   = 393216;
constexpr int EF  = E + N;     // edges + self loops
constexpr int G   = 256;
constexpr int HID = 128;

// ---------------------------------------------------------------------------
// Preprocessing: CSR by destination
// ---------------------------------------------------------------------------
__global__ __launch_bounds__(256) void k_hist(const int* __restrict__ dst,
                                              int* __restrict__ cnt) {
    int e = blockIdx.x * 256 + threadIdx.x;
    if (e < E) atomicAdd(&cnt[dst[e]], 1);
}

// single-block inclusive scan over N=16384 = 1024*16 counts (+1 self loop each)
__global__ __launch_bounds__(1024) void k_scan(const int* __restrict__ cnt,
                                               int* __restrict__ row_ptr) {
    __shared__ int lds[1024];
    int t = threadIdx.x;
    int local[16];
    int s = 0;
    int base = t * 16;
#pragma unroll
    for (int q = 0; q < 16; q++) { local[q] = cnt[base + q] + 1; s += local[q]; }
    lds[t] = s;
    __syncthreads();
    for (int off = 1; off < 1024; off <<= 1) {
        int v = (t >= off) ? lds[t - off] : 0;
        __syncthreads();
        lds[t] += v;
        __syncthreads();
    }
    int run = (t == 0) ? 0 : lds[t - 1];
    if (t == 0) row_ptr[0] = 0;
#pragma unroll
    for (int q = 0; q < 16; q++) { run += local[q]; row_ptr[base + q + 1] = run; }
}

__global__ __launch_bounds__(256) void k_scatter(const int* __restrict__ src,
                                                 const int* __restrict__ dst,
                                                 const int* __restrict__ row_ptr,
                                                 int* __restrict__ fill,
                                                 int* __restrict__ csr_src,
                                                 int* __restrict__ csr_eid) {
    int e = blockIdx.x * 256 + threadIdx.x;
    if (e >= E) return;
    int d = dst[e];
    int pos = row_ptr[d] + atomicAdd(&fill[d], 1);
    csr_src[pos] = src[e];
    csr_eid[pos] = e;
}

__global__ __launch_bounds__(256) void k_selfloop(const int* __restrict__ row_ptr,
                                                  int* __restrict__ csr_src,
                                                  int* __restrict__ csr_eid) {
    int i = blockIdx.x * 256 + threadIdx.x;
    if (i >= N) return;
    int pos = row_ptr[i + 1] - 1;   // last slot of row i is the self loop
    csr_src[pos] = i;
    csr_eid[pos] = E + i;
}

// loop_attr[i] = mean of edge_attr over real incoming edges (0 if none)
__global__ __launch_bounds__(256) void k_loopattr(const int* __restrict__ row_ptr,
                                                  const int* __restrict__ csr_eid,
                                                  const float* __restrict__ edge_attr,
                                                  float* __restrict__ loop_attr) {
    int i = blockIdx.x * 256 + threadIdx.x;
    if (i >= N) return;
    int e0 = row_ptr[i], e1 = row_ptr[i + 1] - 1;   // exclude self loop slot
    float s[6] = {0, 0, 0, 0, 0, 0};
    for (int e = e0; e < e1; e++) {
        int eid = csr_eid[e];
#pragma unroll
        for (int d = 0; d < 6; d++) s[d] += edge_attr[eid * 6 + d];
    }
    float deg = (float)(e1 - e0);
    float inv = 1.0f / fmaxf(deg, 1.0f);
#pragma unroll
    for (int d = 0; d < 6; d++) loop_attr[i * 6 + d] = s[d] * inv;
}

// ---------------------------------------------------------------------------
// Input projection: h = relu(x @ Win + b_in), x is (N,21)
// ---------------------------------------------------------------------------
__global__ __launch_bounds__(128) void k_ingemm(const float* __restrict__ x,
                                                const float* __restrict__ Win,
                                                const float* __restrict__ b_in,
                                                float* __restrict__ h) {
    __shared__ float xs[21];
    int i = blockIdx.x;
    int c = threadIdx.x;
    if (c < 21) xs[c] = x[i * 21 + c];
    __syncthreads();
    float acc = b_in[c];
#pragma unroll
    for (int d = 0; d < 21; d++) acc += xs[d] * Win[d * HID + c];
    h[i * HID + c] = fmaxf(acc, 0.0f);
}

// ---------------------------------------------------------------------------
// Per-layer projections: XL = h@Wl + bl, XR = h@Wr + br  (threads 0-127: XL col,
// 128-255: XR col; each thread does 8 rows)
// ---------------------------------------------------------------------------
__global__ __launch_bounds__(256) void k_gemm_lr(const float* __restrict__ h,
                                                 const float* __restrict__ Wl,
                                                 const float* __restrict__ bl,
                                                 const float* __restrict__ Wr,
                                                 const float* __restrict__ br,
                                                 float* __restrict__ XL,
                                                 float* __restrict__ XR) {
    __shared__ float hs[8][HID];
    int t = threadIdx.x;
    int r0 = blockIdx.x * 8;
#pragma unroll
    for (int q = 0; q < 4; q++) {
        int idx = q * 256 + t;
        hs[idx >> 7][idx & 127] = h[(r0 + (idx >> 7)) * HID + (idx & 127)];
    }
    __syncthreads();
    int c = t & 127;
    bool right = t >= 128;
    const float* W    = right ? Wr : Wl;
    const float* bias = right ? br : bl;
    float* OUT        = right ? XR : XL;
    float b = bias[c];
    float acc[8];
#pragma unroll
    for (int r = 0; r < 8; r++) acc[r] = b;
#pragma unroll 4
    for (int k = 0; k < HID; k++) {
        float w = W[k * HID + c];
#pragma unroll
        for (int r = 0; r < 8; r++) acc[r] += hs[r][k] * w;
    }
#pragma unroll
    for (int r = 0; r < 8; r++) OUT[(r0 + r) * HID + c] = acc[r];
}

// ---------------------------------------------------------------------------
// Edge kernel: one wave per node; lane k owns channels k and k+64.
// Online softmax per head over incoming edges.
// ---------------------------------------------------------------------------
__global__ __launch_bounds__(256) void k_edge(const int* __restrict__ row_ptr,
                                              const int* __restrict__ csr_src,
                                              const int* __restrict__ csr_eid,
                                              const float* __restrict__ edge_attr,
                                              const float* __restrict__ loop_attr,
                                              const float* __restrict__ xl,
                                              const float* __restrict__ xr,
                                              const float* __restrict__ We_l,
                                              const float* __restrict__ att_l,
                                              const float* __restrict__ bconv_l,
                                              float* __restrict__ gout) {
    int wave = (blockIdx.x * blockDim.x + threadIdx.x) >> 6;
    int lane = threadIdx.x & 63;
    if (wave >= N) return;
    int i = wave;
    int ch0 = lane, ch1 = lane + 64;

    float xr0 = xr[i * HID + ch0];
    float xr1 = xr[i * HID + ch1];
    float att0 = att_l[ch0];         // head = lane>>5, c = lane&31
    float att1 = att_l[64 + lane];   // head = 2+(lane>>5)
    float we0[6], we1[6];
#pragma unroll
    for (int d = 0; d < 6; d++) {
        we0[d] = We_l[d * HID + ch0];
        we1[d] = We_l[d * HID + ch1];
    }

    float rm0 = -INFINITY, rm1 = -INFINITY;
    float rd0 = 0.0f, rd1 = 0.0f;
    float acc0 = 0.0f, acc1 = 0.0f;

    int e0 = row_ptr[i], e1 = row_ptr[i + 1];
    for (int e = e0; e < e1; e++) {
        int j   = __builtin_amdgcn_readfirstlane(csr_src[e]);
        int eid = __builtin_amdgcn_readfirstlane(csr_eid[e]);
        const float* ea = (eid < E) ? (edge_attr + (size_t)eid * 6)
                                    : (loop_attr + (size_t)(eid - E) * 6);
        float xl0 = xl[j * HID + ch0];
        float xl1 = xl[j * HID + ch1];
        float ee0 = 0.0f, ee1 = 0.0f;
#pragma unroll
        for (int d = 0; d < 6; d++) {
            float a = ea[d];
            ee0 += a * we0[d];
            ee1 += a * we1[d];
        }
        float m0 = xl0 + xr0 + ee0;
        m0 = m0 > 0.0f ? m0 : 0.2f * m0;
        float m1 = xl1 + xr1 + ee1;
        m1 = m1 > 0.0f ? m1 : 0.2f * m1;
        float p0 = m0 * att0, p1 = m1 * att1;
        // butterfly reduce within each 32-lane group (head-wise)
#pragma unroll
        for (int off = 16; off > 0; off >>= 1) {
            p0 += __shfl_xor(p0, off);
            p1 += __shfl_xor(p1, off);
        }
        // online softmax update (p0/p1 = per-head score, same in all 32 lanes)
        float nm0 = fmaxf(rm0, p0);
        float nm1 = fmaxf(rm1, p1);
        float eo0 = __expf(rm0 - nm0), en0 = __expf(p0 - nm0);
        float eo1 = __expf(rm1 - nm1), en1 = __expf(p1 - nm1);
        rd0 = rd0 * eo0 + en0;
        rd1 = rd1 * eo1 + en1;
        acc0 = acc0 * eo0 + en0 * xl0;
        acc1 = acc1 * eo1 + en1 * xl1;
        rm0 = nm0; rm1 = nm1;
    }
    gout[i * HID + ch0] = acc0 / rd0 + bconv_l[ch0];
    gout[i * HID + ch1] = acc1 / rd1 + bconv_l[ch1];
}

// ---------------------------------------------------------------------------
// BatchNorm over nodes: stats then apply (+optional residual, then relu)
// ---------------------------------------------------------------------------
__global__ __launch_bounds__(256) void k_bnstats(const float* __restrict__ v,
                                                 float* __restrict__ sums) {
    __shared__ float l_s[256], l_q[256];
    int t = threadIdx.x;
    int c = t & 127;
    int half = t >> 7;
    int r = blockIdx.x * 128 + half;
    float s = 0.0f, q = 0.0f;
    for (int it = 0; it < 64; it++, r += 2) {
        float val = v[r * HID + c];
        s += val;
        q += val * val;
    }
    l_s[t] = s; l_q[t] = q;
    __syncthreads();
    if (t < 128) {
        s = l_s[t] + l_s[t + 128];
        q = l_q[t] + l_q[t + 128];
        atomicAdd(&sums[c], s);
        atomicAdd(&sums[128 + c], q);
    }
}

__global__ __launch_bounds__(256) void k_bnapply(const float* __restrict__ g,
                                                 const float* __restrict__ sums,
                                                 const float* __restrict__ gamma,
                                                 const float* __restrict__ beta,
                                                 const float* __restrict__ res,
                                                 float* __restrict__ out) {
    int idx = blockIdx.x * 256 + threadIdx.x;
    int c = idx & 127;
    const float invN = 1.0f / (float)N;
    float mean = sums[c] * invN;
    float var  = sums[128 + c] * invN - mean * mean;
    float inv  = rsqrtf(var + 1e-5f);
    float v = gamma[c] * (g[idx] - mean) * inv + beta[c];
    if (res) v += res[idx];
    out[idx] = fmaxf(v, 0.0f);
}

// ---------------------------------------------------------------------------
// Pool per graph (batch is sorted) + MLP head
// ---------------------------------------------------------------------------
__global__ __launch_bounds__(128) void k_pool(const float* __restrict__ h,
                                              const int* __restrict__ batch,
                                              const float* __restrict__ W1,
                                              const float* __restrict__ b1,
                                              const float* __restrict__ W2,
                                              const float* __restrict__ b2,
                                              float* __restrict__ out) {
    __shared__ float pooled[HID];
    __shared__ float hid[64];
    __shared__ int bounds[2];
    int g = blockIdx.x;
    int t = threadIdx.x;
    if (t < 2) {
        int target = g + t;
        int lo = 0, hi = N;
        while (lo < hi) {
            int mid = (lo + hi) >> 1;
            if (batch[mid] < target) lo = mid + 1; else hi = mid;
        }
        bounds[t] = lo;
    }
    __syncthreads();
    int s = bounds[0], e = bounds[1];
    float acc = 0.0f;
    for (int r = s; r < e; r++) acc += h[r * HID + t];
    float cntf = fmaxf((float)(e - s), 1.0f);
    pooled[t] = acc / cntf;
    __syncthreads();
    if (t < 64) {
        float a = b1[t];
#pragma unroll 4
        for (int c = 0; c < HID; c++) a += pooled[c] * W1[c * 64 + t];
        hid[t] = fmaxf(a, 0.0f);
    }
    __syncthreads();
    if (t < 3) {
        float a = b2[t];
#pragma unroll
        for (int j = 0; j < 64; j++) a += hid[j] * W2[j * 3 + t];
        out[g * 3 + t] = a;
    }
}

// ---------------------------------------------------------------------------
// Launch
// ---------------------------------------------------------------------------
extern "C" void kernel_launch(void* const* d_in, const int* in_sizes, int n_in,
                              void* d_out, int out_size, void* d_ws, size_t ws_size,
                              hipStream_t stream) {
    const float* x         = (const float*)d_in[0];
    const int*   edge_index= (const int*)d_in[1];
    const float* edge_attr = (const float*)d_in[2];
    const int*   batch     = (const int*)d_in[3];
    const float* Win       = (const float*)d_in[4];
    const float* b_in      = (const float*)d_in[5];
    const float* Wl        = (const float*)d_in[6];
    const float* bl        = (const float*)d_in[7];
    const float* Wr        = (const float*)d_in[8];
    const float* br        = (const float*)d_in[9];
    const float* We        = (const float*)d_in[10];
    const float* att       = (const float*)d_in[11];
    const float* bconv     = (const float*)d_in[12];
    const float* gamma     = (const float*)d_in[13];
    const float* beta      = (const float*)d_in[14];
    const float* W1        = (const float*)d_in[15];
    const float* b1        = (const float*)d_in[16];
    const float* W2        = (const float*)d_in[17];
    const float* b2        = (const float*)d_in[18];
    float* out = (float*)d_out;

    const int* src0 = edge_index;
    const int* dst0 = edge_index + E;

    char* ws = (char*)d_ws;
    size_t off = 0;
    auto alloc = [&](size_t bytes) -> void* {
        void* p = ws + off;
        off += (bytes + 255) & ~(size_t)255;
        return p;
    };
    int*   cnt       = (int*)alloc((size_t)2 * N * sizeof(int)); // cnt + fill
    int*   fill      = cnt + N;
    int*   row_ptr   = (int*)alloc((size_t)(N + 1) * sizeof(int));
    int*   csr_src   = (int*)alloc((size_t)EF * sizeof(int));
    int*   csr_eid   = (int*)alloc((size_t)EF * sizeof(int));
    float* loop_attr = (float*)alloc((size_t)N * 6 * sizeof(float));
    float* H0        = (float*)alloc((size_t)N * HID * sizeof(float));
    float* H1        = (float*)alloc((size_t)N * HID * sizeof(float));
    float* XL        = (float*)alloc((size_t)N * HID * sizeof(float));
    float* XR        = (float*)alloc((size_t)N * HID * sizeof(float));
    float* GOUT      = (float*)alloc((size_t)N * HID * sizeof(float));
    float* bnsums    = (float*)alloc(256 * sizeof(float));

    hipMemsetAsync(cnt, 0, (size_t)2 * N * sizeof(int), stream);
    k_hist<<<(E + 255) / 256, 256, 0, stream>>>(dst0, cnt);
    k_scan<<<1, 1024, 0, stream>>>(cnt, row_ptr);
    k_scatter<<<(E + 255) / 256, 256, 0, stream>>>(src0, dst0, row_ptr, fill,
                                                   csr_src, csr_eid);
    k_selfloop<<<(N + 255) / 256, 256, 0, stream>>>(row_ptr, csr_src, csr_eid);
    k_loopattr<<<(N + 255) / 256, 256, 0, stream>>>(row_ptr, csr_eid, edge_attr,
                                                    loop_attr);
    k_ingemm<<<N, 128, 0, stream>>>(x, Win, b_in, H0);

    for (int l = 0; l < 8; l++) {
        const float* hin = (l % 2 == 0) ? H0 : H1;
        k_gemm_lr<<<N / 8, 256, 0, stream>>>(hin,
                                             Wl + (size_t)l * HID * HID, bl + l * HID,
                                             Wr + (size_t)l * HID * HID, br + l * HID,
                                             XL, XR);
        k_edge<<<N / 4, 256, 0, stream>>>(row_ptr, csr_src, csr_eid, edge_attr,
                                          loop_attr, XL, XR,
                                          We + (size_t)l * 6 * HID,
                                          att + (size_t)l * HID,
                                          bconv + (size_t)l * HID, GOUT);
        hipMemsetAsync(bnsums, 0, 256 * sizeof(float), stream);
        k_bnstats<<<128, 256, 0, stream>>>(GOUT, bnsums);
        if (l % 2 == 0) {
            k_bnapply<<<(N * HID) / 256, 256, 0, stream>>>(GOUT, bnsums,
                                                           gamma + l * HID,
                                                           beta + l * HID,
                                                           nullptr, H1);
        } else {
            k_bnapply<<<(N * HID) / 256, 256, 0, stream>>>(GOUT, bnsums,
                                                           gamma + l * HID,
                                                           beta + l * HID,
                                                           H0, H0);
        }
    }
    k_pool<<<G, 128, 0, stream>>>(H0, batch, W1, b1, W2, b2, out);
}

// Round 2
// 753.828 us; speedup vs baseline: 1.4735x; 1.4735x over previous
//
#include <hip/hip_runtime.h>
#include <math.h>

// Problem constants (match reference)
constexpr int N   = 16384;
constexpr int E   = 393216;
constexpr int EF  = E + N;     // edges + self loops
constexpr int G   = 256;
constexpr int HID = 128;

// ---------------------------------------------------------------------------
// 16-lane (DPP row) all-lanes sum via row_ror 1,2,4,8 — pure VALU
// ---------------------------------------------------------------------------
__device__ __forceinline__ float red16(float x) {
    union fi { float f; int i; };
    fi a, b;
    a.f = x;
    b.i = __builtin_amdgcn_mov_dpp(a.i, 0x121, 0xf, 0xf, false); a.f += b.f;
    b.i = __builtin_amdgcn_mov_dpp(a.i, 0x122, 0xf, 0xf, false); a.f += b.f;
    b.i = __builtin_amdgcn_mov_dpp(a.i, 0x124, 0xf, 0xf, false); a.f += b.f;
    b.i = __builtin_amdgcn_mov_dpp(a.i, 0x128, 0xf, 0xf, false); a.f += b.f;
    return a.f;
}

// ---------------------------------------------------------------------------
// Preprocessing: CSR by destination
// ---------------------------------------------------------------------------
__global__ __launch_bounds__(256) void k_hist(const int* __restrict__ dst,
                                              int* __restrict__ cnt) {
    int e = blockIdx.x * 256 + threadIdx.x;
    if (e < E) atomicAdd(&cnt[dst[e]], 1);
}

// single-block inclusive scan over N=16384 = 1024*16 counts (+1 self loop each)
__global__ __launch_bounds__(1024) void k_scan(const int* __restrict__ cnt,
                                               int* __restrict__ row_ptr) {
    __shared__ int lds[1024];
    int t = threadIdx.x;
    int local[16];
    int s = 0;
    int base = t * 16;
#pragma unroll
    for (int q = 0; q < 16; q++) { local[q] = cnt[base + q] + 1; s += local[q]; }
    lds[t] = s;
    __syncthreads();
    for (int off = 1; off < 1024; off <<= 1) {
        int v = (t >= off) ? lds[t - off] : 0;
        __syncthreads();
        lds[t] += v;
        __syncthreads();
    }
    int run = (t == 0) ? 0 : lds[t - 1];
    if (t == 0) row_ptr[0] = 0;
#pragma unroll
    for (int q = 0; q < 16; q++) { run += local[q]; row_ptr[base + q + 1] = run; }
}

__global__ __launch_bounds__(256) void k_scatter(const int* __restrict__ src,
                                                 const int* __restrict__ dst,
                                                 const int* __restrict__ row_ptr,
                                                 int* __restrict__ fill,
                                                 int* __restrict__ csr_src,
                                                 int* __restrict__ csr_eid) {
    int e = blockIdx.x * 256 + threadIdx.x;
    if (e >= E) return;
    int d = dst[e];
    int pos = row_ptr[d] + atomicAdd(&fill[d], 1);
    csr_src[pos] = src[e];
    csr_eid[pos] = e;
}

__global__ __launch_bounds__(256) void k_selfloop(const int* __restrict__ row_ptr,
                                                  int* __restrict__ csr_src,
                                                  int* __restrict__ csr_eid) {
    int i = blockIdx.x * 256 + threadIdx.x;
    if (i >= N) return;
    int pos = row_ptr[i + 1] - 1;   // last slot of row i is the self loop
    csr_src[pos] = i;
    csr_eid[pos] = E + i;
}

// loop_attr[i] = mean of edge_attr over real incoming edges (0 if none)
__global__ __launch_bounds__(256) void k_loopattr(const int* __restrict__ row_ptr,
                                                  const int* __restrict__ csr_eid,
                                                  const float* __restrict__ edge_attr,
                                                  float* __restrict__ loop_attr) {
    int i = blockIdx.x * 256 + threadIdx.x;
    if (i >= N) return;
    int e0 = row_ptr[i], e1 = row_ptr[i + 1] - 1;   // exclude self loop slot
    float s[6] = {0, 0, 0, 0, 0, 0};
    for (int e = e0; e < e1; e++) {
        int eid = csr_eid[e];
#pragma unroll
        for (int d = 0; d < 6; d++) s[d] += edge_attr[eid * 6 + d];
    }
    float deg = (float)(e1 - e0);
    float inv = 1.0f / fmaxf(deg, 1.0f);
#pragma unroll
    for (int d = 0; d < 6; d++) loop_attr[i * 6 + d] = s[d] * inv;
}

// Gather edge_attr (or loop_attr for self loops) into CSR slot order, pad to 8
__global__ __launch_bounds__(256) void k_build_ea(const int* __restrict__ csr_eid,
                                                  const float* __restrict__ edge_attr,
                                                  const float* __restrict__ loop_attr,
                                                  float* __restrict__ csr_ea) {
    int p = blockIdx.x * 256 + threadIdx.x;
    if (p >= EF) return;
    int eid = csr_eid[p];
    const float* s = (eid < E) ? (edge_attr + (size_t)eid * 6)
                               : (loop_attr + (size_t)(eid - E) * 6);
    float4 a = {s[0], s[1], s[2], s[3]};
    float4 b = {s[4], s[5], 0.0f, 0.0f};
    float4* dst = (float4*)(csr_ea + (size_t)p * 8);
    dst[0] = a;
    dst[1] = b;
}

// ---------------------------------------------------------------------------
// Input projection: h = relu(x @ Win + b_in), x is (N,21)
// ---------------------------------------------------------------------------
__global__ __launch_bounds__(128) void k_ingemm(const float* __restrict__ x,
                                                const float* __restrict__ Win,
                                                const float* __restrict__ b_in,
                                                float* __restrict__ h) {
    __shared__ float xs[21];
    int i = blockIdx.x;
    int c = threadIdx.x;
    if (c < 21) xs[c] = x[i * 21 + c];
    __syncthreads();
    float acc = b_in[c];
#pragma unroll
    for (int d = 0; d < 21; d++) acc += xs[d] * Win[d * HID + c];
    h[i * HID + c] = fmaxf(acc, 0.0f);
}

// ---------------------------------------------------------------------------
// Per-layer projections: XL = h@Wl + bl, XR = h@Wr + br
// 16-row tile per block; thread owns (matrix, col-pair, 8 rows)
// ---------------------------------------------------------------------------
__global__ __launch_bounds__(256) void k_gemm_lr(const float* __restrict__ h,
                                                 const float* __restrict__ Wl,
                                                 const float* __restrict__ bl,
                                                 const float* __restrict__ Wr,
                                                 const float* __restrict__ br,
                                                 float* __restrict__ XL,
                                                 float* __restrict__ XR) {
    __shared__ float hs[16][HID];
    int t = threadIdx.x;
    int r0 = blockIdx.x * 16;
    {
        int row = t >> 4;
        int col = (t & 15) * 8;
        const float4* src = (const float4*)&h[(size_t)(r0 + row) * HID + col];
        float4* dst = (float4*)&hs[row][col];
        dst[0] = src[0];
        dst[1] = src[1];
    }
    __syncthreads();
    bool right = t >= 128;
    int cp = (t & 63) * 2;
    int rbase = ((t >> 6) & 1) * 8;
    const float* W    = right ? Wr : Wl;
    const float* bias = right ? br : bl;
    float* OUT        = right ? XR : XL;
    float b0 = bias[cp], b1 = bias[cp + 1];
    float acc0[8], acc1[8];
#pragma unroll
    for (int r = 0; r < 8; r++) { acc0[r] = b0; acc1[r] = b1; }
    for (int k = 0; k < HID; k += 4) {
        float4 h4[8];
#pragma unroll
        for (int r = 0; r < 8; r++) h4[r] = *(const float4*)&hs[rbase + r][k];
#pragma unroll
        for (int kk = 0; kk < 4; kk++) {
            float2 w = *(const float2*)&W[(size_t)(k + kk) * HID + cp];
#pragma unroll
            for (int r = 0; r < 8; r++) {
                float hv = ((const float*)&h4[r])[kk];
                acc0[r] = fmaf(hv, w.x, acc0[r]);
                acc1[r] = fmaf(hv, w.y, acc1[r]);
            }
        }
    }
#pragma unroll
    for (int r = 0; r < 8; r++) {
        float2 o = {acc0[r], acc1[r]};
        *(float2*)&OUT[(size_t)(r0 + rbase + r) * HID + cp] = o;
    }
}

// ---------------------------------------------------------------------------
// Edge kernel: one wave per node. Lane = head*16 + s; owns channels
// (h*32+2s, h*32+2s+1). 4-step DPP row reduction for the attention dot;
// 4-edge-batched online softmax. bconv omitted (cancels in BN).
// ---------------------------------------------------------------------------
__global__ __launch_bounds__(256) void k_edge(const int* __restrict__ row_ptr,
                                              const int* __restrict__ csr_src,
                                              const float* __restrict__ csr_ea,
                                              const float* __restrict__ xl,
                                              const float* __restrict__ xr,
                                              const float* __restrict__ We_l,
                                              const float* __restrict__ att_l,
                                              float* __restrict__ gout) {
    int wave = (blockIdx.x * blockDim.x + threadIdx.x) >> 6;
    int lane = threadIdx.x & 63;
    if (wave >= N) return;
    int i = wave;
    int hh = lane >> 4;
    int ss = lane & 15;
    int ch0 = hh * 32 + 2 * ss;

    float2 xr2 = *(const float2*)&xr[(size_t)i * HID + ch0];
    float a0 = att_l[ch0], a1 = att_l[ch0 + 1];
    float we0[6], we1[6];
#pragma unroll
    for (int d = 0; d < 6; d++) {
        float2 w = *(const float2*)&We_l[d * HID + ch0];
        we0[d] = w.x;
        we1[d] = w.y;
    }

    float rm = -INFINITY, rd = 0.0f, acc0 = 0.0f, acc1 = 0.0f;

    int e0 = __builtin_amdgcn_readfirstlane(row_ptr[i]);
    int e1 = __builtin_amdgcn_readfirstlane(row_ptr[i + 1]);

    for (int e = e0; e < e1; e += 4) {
        float p[4], v0[4], v1[4];
#pragma unroll
        for (int k = 0; k < 4; k++) {
            int ee = e + k;
            int ec = (ee < e1) ? ee : (e1 - 1);
            int j = __builtin_amdgcn_readfirstlane(csr_src[ec]);
            const float4* ea4 = (const float4*)(csr_ea + (size_t)ec * 8);
            float4 eaA = ea4[0];
            float4 eaB = ea4[1];
            float2 xl2 = *(const float2*)&xl[(size_t)j * HID + ch0];
            float s0 = eaA.x * we0[0], s1 = eaA.x * we1[0];
            s0 = fmaf(eaA.y, we0[1], s0); s1 = fmaf(eaA.y, we1[1], s1);
            s0 = fmaf(eaA.z, we0[2], s0); s1 = fmaf(eaA.z, we1[2], s1);
            s0 = fmaf(eaA.w, we0[3], s0); s1 = fmaf(eaA.w, we1[3], s1);
            s0 = fmaf(eaB.x, we0[4], s0); s1 = fmaf(eaB.x, we1[4], s1);
            s0 = fmaf(eaB.y, we0[5], s0); s1 = fmaf(eaB.y, we1[5], s1);
            float m0 = xl2.x + xr2.x + s0;
            float m1 = xl2.y + xr2.y + s1;
            m0 = fmaxf(m0, 0.2f * m0);       // leaky relu (both signs)
            m1 = fmaxf(m1, 0.2f * m1);
            float pv = m0 * a0;
            pv = fmaf(m1, a1, pv);
            pv = red16(pv);                  // per-head score, all 16 lanes
            p[k] = (ee < e1) ? pv : -INFINITY;
            v0[k] = xl2.x;
            v1[k] = xl2.y;
        }
        float bm = fmaxf(fmaxf(p[0], p[1]), fmaxf(p[2], p[3]));
        float nm = fmaxf(rm, bm);
        float sc = __expf(rm - nm);
        rd *= sc; acc0 *= sc; acc1 *= sc;
#pragma unroll
        for (int k = 0; k < 4; k++) {
            float ek = __expf(p[k] - nm);
            rd += ek;
            acc0 = fmaf(ek, v0[k], acc0);
            acc1 = fmaf(ek, v1[k], acc1);
        }
        rm = nm;
    }
    float inv = 1.0f / rd;
    float2 o = {acc0 * inv, acc1 * inv};
    *(float2*)&gout[(size_t)i * HID + ch0] = o;
}

// ---------------------------------------------------------------------------
// BatchNorm over nodes: stats then apply (+optional residual, then relu)
// ---------------------------------------------------------------------------
__global__ __launch_bounds__(256) void k_bnstats(const float* __restrict__ v,
                                                 float* __restrict__ sums) {
    __shared__ float l_s[256], l_q[256];
    int t = threadIdx.x;
    int c = t & 127;
    int half = t >> 7;
    int r = blockIdx.x * 128 + half;
    float s = 0.0f, q = 0.0f;
    for (int it = 0; it < 64; it++, r += 2) {
        float val = v[(size_t)r * HID + c];
        s += val;
        q += val * val;
    }
    l_s[t] = s; l_q[t] = q;
    __syncthreads();
    if (t < 128) {
        s = l_s[t] + l_s[t + 128];
        q = l_q[t] + l_q[t + 128];
        atomicAdd(&sums[c], s);
        atomicAdd(&sums[128 + c], q);
    }
}

__global__ __launch_bounds__(256) void k_bnapply(const float* __restrict__ g,
                                                 const float* __restrict__ sums,
                                                 const float* __restrict__ gamma,
                                                 const float* __restrict__ beta,
                                                 const float* __restrict__ res,
                                                 float* __restrict__ out) {
    int idx4 = (blockIdx.x * 256 + threadIdx.x) * 4;
    int c = idx4 & 127;
    const float invN = 1.0f / (float)N;
    float4 gv = *(const float4*)&g[idx4];
    float4 s4 = *(const float4*)&sums[c];
    float4 q4 = *(const float4*)&sums[128 + c];
    float4 gm = *(const float4*)&gamma[c];
    float4 bt = *(const float4*)&beta[c];
    float4 o;
    {
        float mean = s4.x * invN, var = q4.x * invN - mean * mean;
        o.x = gm.x * (gv.x - mean) * rsqrtf(var + 1e-5f) + bt.x;
        mean = s4.y * invN; var = q4.y * invN - mean * mean;
        o.y = gm.y * (gv.y - mean) * rsqrtf(var + 1e-5f) + bt.y;
        mean = s4.z * invN; var = q4.z * invN - mean * mean;
        o.z = gm.z * (gv.z - mean) * rsqrtf(var + 1e-5f) + bt.z;
        mean = s4.w * invN; var = q4.w * invN - mean * mean;
        o.w = gm.w * (gv.w - mean) * rsqrtf(var + 1e-5f) + bt.w;
    }
    if (res) {
        float4 r4 = *(const float4*)&res[idx4];
        o.x += r4.x; o.y += r4.y; o.z += r4.z; o.w += r4.w;
    }
    o.x = fmaxf(o.x, 0.0f);
    o.y = fmaxf(o.y, 0.0f);
    o.z = fmaxf(o.z, 0.0f);
    o.w = fmaxf(o.w, 0.0f);
    *(float4*)&out[idx4] = o;
}

// ---------------------------------------------------------------------------
// Pool per graph (batch is sorted) + MLP head
// ---------------------------------------------------------------------------
__global__ __launch_bounds__(128) void k_pool(const float* __restrict__ h,
                                              const int* __restrict__ batch,
                                              const float* __restrict__ W1,
                                              const float* __restrict__ b1,
                                              const float* __restrict__ W2,
                                              const float* __restrict__ b2,
                                              float* __restrict__ out) {
    __shared__ float pooled[HID];
    __shared__ float hid[64];
    __shared__ int bounds[2];
    int g = blockIdx.x;
    int t = threadIdx.x;
    if (t < 2) {
        int target = g + t;
        int lo = 0, hi = N;
        while (lo < hi) {
            int mid = (lo + hi) >> 1;
            if (batch[mid] < target) lo = mid + 1; else hi = mid;
        }
        bounds[t] = lo;
    }
    __syncthreads();
    int s = bounds[0], e = bounds[1];
    float acc = 0.0f;
    for (int r = s; r < e; r++) acc += h[(size_t)r * HID + t];
    float cntf = fmaxf((float)(e - s), 1.0f);
    pooled[t] = acc / cntf;
    __syncthreads();
    if (t < 64) {
        float a = b1[t];
#pragma unroll 4
        for (int c = 0; c < HID; c++) a += pooled[c] * W1[c * 64 + t];
        hid[t] = fmaxf(a, 0.0f);
    }
    __syncthreads();
    if (t < 3) {
        float a = b2[t];
#pragma unroll
        for (int j = 0; j < 64; j++) a += hid[j] * W2[j * 3 + t];
        out[g * 3 + t] = a;
    }
}

// ---------------------------------------------------------------------------
// Launch
// ---------------------------------------------------------------------------
extern "C" void kernel_launch(void* const* d_in, const int* in_sizes, int n_in,
                              void* d_out, int out_size, void* d_ws, size_t ws_size,
                              hipStream_t stream) {
    const float* x         = (const float*)d_in[0];
    const int*   edge_index= (const int*)d_in[1];
    const float* edge_attr = (const float*)d_in[2];
    const int*   batch     = (const int*)d_in[3];
    const float* Win       = (const float*)d_in[4];
    const float* b_in      = (const float*)d_in[5];
    const float* Wl        = (const float*)d_in[6];
    const float* bl        = (const float*)d_in[7];
    const float* Wr        = (const float*)d_in[8];
    const float* br        = (const float*)d_in[9];
    const float* We        = (const float*)d_in[10];
    const float* att       = (const float*)d_in[11];
    const float* gamma     = (const float*)d_in[13];
    const float* beta      = (const float*)d_in[14];
    const float* W1        = (const float*)d_in[15];
    const float* b1        = (const float*)d_in[16];
    const float* W2        = (const float*)d_in[17];
    const float* b2        = (const float*)d_in[18];
    float* out = (float*)d_out;

    const int* src0 = edge_index;
    const int* dst0 = edge_index + E;

    char* ws = (char*)d_ws;
    size_t off = 0;
    auto alloc = [&](size_t bytes) -> void* {
        void* p = ws + off;
        off += (bytes + 255) & ~(size_t)255;
        return p;
    };
    // cnt+fill (2N ints = 128KiB, 256-aligned) then bnsums (8 layers x 256 f)
    // must stay adjacent: one memset covers all three.
    int*   cnt       = (int*)alloc((size_t)2 * N * sizeof(int));
    int*   fill      = cnt + N;
    float* bnsums    = (float*)alloc((size_t)8 * 256 * sizeof(float));
    int*   row_ptr   = (int*)alloc((size_t)(N + 1) * sizeof(int));
    int*   csr_src   = (int*)alloc((size_t)EF * sizeof(int));
    int*   csr_eid   = (int*)alloc((size_t)EF * sizeof(int));
    float* csr_ea    = (float*)alloc((size_t)EF * 8 * sizeof(float));
    float* loop_attr = (float*)alloc((size_t)N * 6 * sizeof(float));
    float* H0        = (float*)alloc((size_t)N * HID * sizeof(float));
    float* H1        = (float*)alloc((size_t)N * HID * sizeof(float));
    float* XL        = (float*)alloc((size_t)N * HID * sizeof(float));
    float* XR        = (float*)alloc((size_t)N * HID * sizeof(float));
    float* GOUT      = (float*)alloc((size_t)N * HID * sizeof(float));

    hipMemsetAsync(cnt, 0, (size_t)2 * N * sizeof(int) + 8 * 256 * sizeof(float),
                   stream);
    k_hist<<<(E + 255) / 256, 256, 0, stream>>>(dst0, cnt);
    k_scan<<<1, 1024, 0, stream>>>(cnt, row_ptr);
    k_scatter<<<(E + 255) / 256, 256, 0, stream>>>(src0, dst0, row_ptr, fill,
                                                   csr_src, csr_eid);
    k_selfloop<<<(N + 255) / 256, 256, 0, stream>>>(row_ptr, csr_src, csr_eid);
    k_loopattr<<<(N + 255) / 256, 256, 0, stream>>>(row_ptr, csr_eid, edge_attr,
                                                    loop_attr);
    k_build_ea<<<(EF + 255) / 256, 256, 0, stream>>>(csr_eid, edge_attr,
                                                     loop_attr, csr_ea);
    k_ingemm<<<N, 128, 0, stream>>>(x, Win, b_in, H0);

    for (int l = 0; l < 8; l++) {
        const float* hin = (l % 2 == 0) ? H0 : H1;
        k_gemm_lr<<<N / 16, 256, 0, stream>>>(hin,
                                              Wl + (size_t)l * HID * HID, bl + l * HID,
                                              Wr + (size_t)l * HID * HID, br + l * HID,
                                              XL, XR);
        k_edge<<<N / 4, 256, 0, stream>>>(row_ptr, csr_src, csr_ea,
                                          XL, XR,
                                          We + (size_t)l * 6 * HID,
                                          att + (size_t)l * HID, GOUT);
        float* bns = bnsums + l * 256;
        k_bnstats<<<128, 256, 0, stream>>>(GOUT, bns);
        if (l % 2 == 0) {
            k_bnapply<<<(N * HID) / 1024, 256, 0, stream>>>(GOUT, bns,
                                                            gamma + l * HID,
                                                            beta + l * HID,
                                                            nullptr, H1);
        } else {
            k_bnapply<<<(N * HID) / 1024, 256, 0, stream>>>(GOUT, bns,
                                                            gamma + l * HID,
                                                            beta + l * HID,
                                                            H0, H0);
        }
    }
    k_pool<<<G, 128, 0, stream>>>(H0, batch, W1, b1, W2, b2, out);
}